// Round 6
// baseline (301.337 us; speedup 1.0000x reference)
//
#include <hip/hip_runtime.h>
#include <hip/hip_bf16.h>
#include <math.h>

#define S_NODES 255
#define B_TREES 256
#define F_IN 64
#define H_DIM 128

typedef __attribute__((ext_vector_type(8))) short short8;
typedef __attribute__((ext_vector_type(4))) float f32x4;

__device__ __forceinline__ float fsig(float x) {
    float e = __expf(-x);
    return __builtin_amdgcn_rcpf(1.0f + e);
}
__device__ __forceinline__ float ftanh_(float x) {
    x = fminf(fmaxf(x, -15.0f), 15.0f);
    float e = __expf(2.0f * x);
    return (e - 1.0f) * __builtin_amdgcn_rcpf(e + 1.0f);
}
__device__ __forceinline__ unsigned short f2bf(float x) {
    union { __hip_bfloat16 b; unsigned short u; } v; v.b = __float2bfloat16(x); return v.u;
}
__device__ __forceinline__ float bf2f(unsigned short u) {
    union { unsigned int w; float f; } v; v.w = ((unsigned int)u) << 16; return v.f;
}

// ---------------- prep: split-bf16 B matrices (fragment-contiguous) ----------------
// Btu[n][384] shorts: k''<192 = hi, >=192 = lo.  k<128: U rows; [128,192): W rows
//   cols n<384: U_iou / 0.5*W_iou ; n>=384: U_f / W_f
// Btl[n][128] shorts: k<64 hi, >=64 lo of W_iou (leaf), n<384
__global__ __launch_bounds__(256) void prep_bt(
    const float* __restrict__ U_iou, const float* __restrict__ U_f,
    const float* __restrict__ W_iou, const float* __restrict__ W_f,
    unsigned short* __restrict__ Btu, unsigned short* __restrict__ Btl)
{
    int t = blockIdx.x * 256 + threadIdx.x;
    if (t < 512 * 192) {
        int k = t >> 9, n = t & 511;
        float v;
        if (k < 128) v = (n < 384) ? U_iou[k * 384 + n] : U_f[k * 128 + (n - 384)];
        else {
            int kf = k - 128;
            v = (n < 384) ? 0.5f * W_iou[kf * 384 + n] : W_f[kf * 128 + (n - 384)];
        }
        unsigned short hi = f2bf(v);
        Btu[n * 384 + k] = hi;
        Btu[n * 384 + 192 + k] = f2bf(v - bf2f(hi));
    } else {
        int t2 = t - 512 * 192;   // < 384*64
        int k = t2 & 63, n = t2 >> 6;
        float v = W_iou[k * 384 + n];
        unsigned short hi = f2bf(v);
        Btl[n * 128 + k] = hi;
        Btl[n * 128 + 64 + k] = f2bf(v - bf2f(hi));
    }
}

// ---------------- pack fp32 weights for the top kernel ----------------
__global__ __launch_bounds__(256) void pack_weights(
    const float* __restrict__ W_iou, const float* __restrict__ W_f,
    const float* __restrict__ U_iou, const float* __restrict__ U_f,
    float4* __restrict__ Wp, float4* __restrict__ Up)
{
    int t = blockIdx.x * 256 + threadIdx.x;
    if (t < F_IN * H_DIM) {
        int k = t >> 7, j = t & 127;
        Wp[t] = make_float4(W_iou[k * 384 + j], W_iou[k * 384 + 128 + j],
                            W_iou[k * 384 + 256 + j], W_f[k * H_DIM + j]);
    } else {
        int t2 = t - F_IN * H_DIM;
        int k = t2 >> 7, j = t2 & 127;
        Up[t2] = make_float4(U_iou[k * 384 + j], U_iou[k * 384 + 128 + j],
                             U_iou[k * 384 + 256 + j], U_f[k * H_DIM + j]);
    }
}

#define MFMA(a, b, c) __builtin_amdgcn_mfma_f32_16x16x32_bf16(a, b, c, 0, 0, 0)

// ---------------- leaf GEMM: 32 leaves/block; direct-global B frags ----------------
// Wave w owns j in [32w,32w+32) for gates i,o,u (6 col-tiles of 16).
__global__ __launch_bounds__(256, 4) void leafgemm(
    const float* __restrict__ feat, const unsigned short* __restrict__ Btl,
    const float* __restrict__ b_iou,
    float* __restrict__ h, float* __restrict__ c_out,
    unsigned int* __restrict__ h2out)
{
    __shared__ __align__(16) char Alb[32 * 256];
    const int tid = threadIdx.x;
    const int w = tid >> 6, l = tid & 63;
    const int l15 = l & 15, l4 = l >> 4;
    const int NB = blockIdx.x << 5;

    // A stage: 32 rows x 16 chunks (0..7 feat-hi, 8..15 feat-lo); 1 task/thread
    {
        int row = tid >> 3, o = tid & 7;
        int leafidx = NB + row;
        int tree = leafidx >> 7;
        int grow = tree * S_NODES + 127 + (leafidx & 127);
        const float* fp = feat + (size_t)grow * F_IN + (o << 3);
        float4 va = *(const float4*)(fp);
        float4 vb = *(const float4*)(fp + 4);
        float vv[8] = {va.x, va.y, va.z, va.w, vb.x, vb.y, vb.z, vb.w};
        unsigned int qh[4], ql[4];
        #pragma unroll
        for (int e = 0; e < 4; ++e) {
            unsigned short h0 = f2bf(vv[2*e]),   h1 = f2bf(vv[2*e+1]);
            unsigned short l0 = f2bf(vv[2*e]   - bf2f(h0));
            unsigned short l1 = f2bf(vv[2*e+1] - bf2f(h1));
            qh[e] = (unsigned)h0 | ((unsigned)h1 << 16);
            ql[e] = (unsigned)l0 | ((unsigned)l1 << 16);
        }
        char* arow = Alb + (row << 8);
        int sw = (row & 7) << 4;
        *(uint4*)(arow + ((o << 4) ^ sw)) = make_uint4(qh[0], qh[1], qh[2], qh[3]);
        *(uint4*)(arow + (((8 + o) << 4) ^ sw)) = make_uint4(ql[0], ql[1], ql[2], ql[3]);
    }
    __syncthreads();

    f32x4 accA[6], accB[6];
    #pragma unroll
    for (int i = 0; i < 6; ++i) { accA[i] = (f32x4){0,0,0,0}; accB[i] = (f32x4){0,0,0,0}; }

    const int rA0 = l15, rA1 = 16 + l15;
    const int swzA0 = (rA0 & 7) << 4, swzA1 = (rA1 & 7) << 4;
    int nct[6];
    #pragma unroll
    for (int ct = 0; ct < 6; ++ct)
        nct[ct] = ((ct >> 1) << 7) + (w << 5) + ((ct & 1) << 4) + l15;

    #pragma unroll
    for (int s = 0; s < 2; ++s) {
        int ch = (s << 2) + l4;
        short8 ah0 = *(const short8*)(Alb + (rA0 << 8) + ((ch << 4) ^ swzA0));
        short8 ah1 = *(const short8*)(Alb + (rA1 << 8) + ((ch << 4) ^ swzA1));
        short8 al0 = *(const short8*)(Alb + (rA0 << 8) + (((8 + ch) << 4) ^ swzA0));
        short8 al1 = *(const short8*)(Alb + (rA1 << 8) + (((8 + ch) << 4) ^ swzA1));
        #pragma unroll
        for (int ct = 0; ct < 6; ++ct) {
            const char* bp = (const char*)Btl + (size_t)nct[ct] * 256 + (ch << 4);
            short8 bh = *(const short8*)(bp);
            short8 bl = *(const short8*)(bp + 128);
            accA[ct] = MFMA(ah0, bh, accA[ct]);
            accB[ct] = MFMA(ah1, bh, accB[ct]);
            accA[ct] = MFMA(al0, bh, accA[ct]);
            accB[ct] = MFMA(al1, bh, accB[ct]);
            accA[ct] = MFMA(ah0, bl, accA[ct]);
            accB[ct] = MFMA(ah1, bl, accB[ct]);
        }
    }

    // epilogue: gates are lane-local (row = l4*4+rr, col = nct)
    const int jb = (w << 5) + l15;
    #define LEPI(ACC, HALF)                                                     \
        _Pragma("unroll")                                                       \
        for (int rr = 0; rr < 4; ++rr) {                                        \
            int leafrow = ((HALF) << 4) + (l4 << 2) + rr;                       \
            int leafidx = NB + leafrow;                                         \
            int tree = leafidx >> 7;                                            \
            size_t grow = (size_t)(tree * S_NODES + 127 + (leafidx & 127));     \
            float iv = ACC[0 + t][rr] + bi;                                     \
            float ov = ACC[2 + t][rr] + bo;                                     \
            float uv = ACC[4 + t][rr] + bu;                                     \
            float cn = fsig(iv) * ftanh_(uv);                                   \
            float hn = fsig(ov) * ftanh_(cn);                                   \
            h[grow * 128 + j] = hn;                                             \
            c_out[grow * 128 + j] = cn;                                         \
            unsigned short h2h = f2bf(hn);                                      \
            unsigned short h2l = f2bf(hn - bf2f(h2h));                          \
            h2out[grow * 128 + j] = (unsigned)h2h | ((unsigned)h2l << 16);      \
        }
    #pragma unroll
    for (int t = 0; t < 2; ++t) {
        int j = jb + (t << 4);
        float bi = b_iou[j], bo = b_iou[128 + j], bu = b_iou[256 + j];
        LEPI(accA, 0)
        LEPI(accB, 1)
    }
    #undef LEPI
}

// ---------------- internal-level GEMM: 16 nodes (32 child rows)/block ----------------
// A-row = [h_child(128) | feat_parent(64)] split-bf16 in LDS (staged once).
// B frags loaded directly from global Btu. Wave w owns j in [32w,32w+32) x 4 gates.
__global__ __launch_bounds__(256, 3) void ugemm(
    const float* __restrict__ feat, const unsigned int* __restrict__ h2,
    const unsigned short* __restrict__ Btu,
    const float* __restrict__ b_iou, const float* __restrict__ b_f,
    float* __restrict__ h, float* __restrict__ c_io,
    unsigned int* __restrict__ h2out,
    int Lstart, int Lbits)
{
    __shared__ __align__(16) char Alb[32 * 768];
    const int tid = threadIdx.x;
    const int w = tid >> 6, l = tid & 63;
    const int l15 = l & 15, l4 = l >> 4;
    const int NB = blockIdx.x << 4;
    const int mask = (1 << Lbits) - 1;

    // ---- A stage: 32 rows x 48 chunks; 3 tasks/thread ----
    // chunks: 0..15 h-hi, 16..23 feat-hi, 24..39 h-lo, 40..47 feat-lo
    #pragma unroll
    for (int i = 0; i < 3; ++i) {
        int tsk = tid + (i << 8);
        if (tsk < 512) {
            int row = tsk >> 4, o = tsk & 15;
            int node = NB + (row >> 1);
            int tree = node >> Lbits;
            int local = Lstart + (node & mask);
            int growc = tree * S_NODES + 2 * local + 1 + (row & 1);
            const unsigned int* hp = h2 + (size_t)growc * 128 + (o << 3);
            uint4 a = *(const uint4*)(hp);
            uint4 b = *(const uint4*)(hp + 4);
            uint4 vh, vl;
            vh.x = (a.x & 0xffffu) | (a.y << 16);
            vh.y = (a.z & 0xffffu) | (a.w << 16);
            vh.z = (b.x & 0xffffu) | (b.y << 16);
            vh.w = (b.z & 0xffffu) | (b.w << 16);
            vl.x = (a.x >> 16) | (a.y & 0xffff0000u);
            vl.y = (a.z >> 16) | (a.w & 0xffff0000u);
            vl.z = (b.x >> 16) | (b.y & 0xffff0000u);
            vl.w = (b.z >> 16) | (b.w & 0xffff0000u);
            char* arow = Alb + row * 768;
            int sw = (row & 7) << 4;
            *(uint4*)(arow + ((o << 4) ^ sw)) = vh;
            *(uint4*)(arow + (((24 + o) << 4) ^ sw)) = vl;
        } else {
            int t2 = tsk - 512;   // < 256
            int row = t2 >> 3, o = t2 & 7;
            int node = NB + (row >> 1);
            int tree = node >> Lbits;
            int local = Lstart + (node & mask);
            int growp = tree * S_NODES + local;
            const float* fp = feat + (size_t)growp * F_IN + (o << 3);
            float4 va = *(const float4*)(fp);
            float4 vb = *(const float4*)(fp + 4);
            float vv[8] = {va.x, va.y, va.z, va.w, vb.x, vb.y, vb.z, vb.w};
            unsigned int qh[4], ql[4];
            #pragma unroll
            for (int e = 0; e < 4; ++e) {
                unsigned short h0 = f2bf(vv[2*e]),   h1 = f2bf(vv[2*e+1]);
                unsigned short l0 = f2bf(vv[2*e]   - bf2f(h0));
                unsigned short l1 = f2bf(vv[2*e+1] - bf2f(h1));
                qh[e] = (unsigned)h0 | ((unsigned)h1 << 16);
                ql[e] = (unsigned)l0 | ((unsigned)l1 << 16);
            }
            char* arow = Alb + row * 768;
            int sw = (row & 7) << 4;
            *(uint4*)(arow + (((16 + o) << 4) ^ sw)) = make_uint4(qh[0], qh[1], qh[2], qh[3]);
            *(uint4*)(arow + (((40 + o) << 4) ^ sw)) = make_uint4(ql[0], ql[1], ql[2], ql[3]);
        }
    }
    __syncthreads();

    f32x4 accA[8], accB[8];
    #pragma unroll
    for (int i = 0; i < 8; ++i) { accA[i] = (f32x4){0,0,0,0}; accB[i] = (f32x4){0,0,0,0}; }

    const int rA0 = l15, rA1 = 16 + l15;
    const int swzA0 = (rA0 & 7) << 4, swzA1 = (rA1 & 7) << 4;
    int nct[8];
    #pragma unroll
    for (int ct = 0; ct < 8; ++ct)
        nct[ct] = ((ct >> 1) << 7) + (w << 5) + ((ct & 1) << 4) + l15;

    #pragma unroll 2
    for (int s = 0; s < 6; ++s) {
        int ch = (s << 2) + l4;
        short8 ah0 = *(const short8*)(Alb + rA0 * 768 + ((ch << 4) ^ swzA0));
        short8 ah1 = *(const short8*)(Alb + rA1 * 768 + ((ch << 4) ^ swzA1));
        short8 al0 = *(const short8*)(Alb + rA0 * 768 + (((24 + ch) << 4) ^ swzA0));
        short8 al1 = *(const short8*)(Alb + rA1 * 768 + (((24 + ch) << 4) ^ swzA1));
        #pragma unroll
        for (int ct = 0; ct < 8; ++ct) {
            const char* bp = (const char*)Btu + (size_t)nct[ct] * 768 + (ch << 4);
            short8 bh = *(const short8*)(bp);
            short8 bl = *(const short8*)(bp + 384);
            accA[ct] = MFMA(ah0, bh, accA[ct]);
            accB[ct] = MFMA(ah1, bh, accB[ct]);
            accA[ct] = MFMA(al0, bh, accA[ct]);
            accB[ct] = MFMA(al1, bh, accB[ct]);
            accA[ct] = MFMA(ah0, bl, accA[ct]);
            accB[ct] = MFMA(ah1, bl, accB[ct]);
        }
    }

    // ---- epilogue: all gates lane-local; row-pair sum within f32x4 ----
    const int jb = (w << 5) + l15;
    #define EPI(ACC, HALF)                                                          \
        _Pragma("unroll")                                                           \
        for (int p = 0; p < 2; ++p) {                                               \
            int node = NB + ((HALF) << 3) + (l4 << 1) + p;                          \
            int tree = node >> Lbits;                                               \
            int local = Lstart + (node & mask);                                     \
            size_t gp = (size_t)(tree * S_NODES + local);                           \
            size_t gl = (size_t)(tree * S_NODES + 2 * local + 1);                   \
            float iv = ACC[0 + t][2*p] + ACC[0 + t][2*p + 1] + bi;                  \
            float ov = ACC[2 + t][2*p] + ACC[2 + t][2*p + 1] + bo;                  \
            float uv = ACC[4 + t][2*p] + ACC[4 + t][2*p + 1] + bu;                  \
            float flv = fsig(ACC[6 + t][2*p] + bfv);                                \
            float frv = fsig(ACC[6 + t][2*p + 1] + bfv);                            \
            float cl = c_io[gl * 128 + j];                                          \
            float cr = c_io[(gl + 1) * 128 + j];                                    \
            float cn = fsig(iv) * ftanh_(uv) + flv * cl + frv * cr;                 \
            float hn = fsig(ov) * ftanh_(cn);                                       \
            h[gp * 128 + j] = hn;                                                   \
            c_io[gp * 128 + j] = cn;                                                \
            unsigned short h2h = f2bf(hn);                                          \
            unsigned short h2l = f2bf(hn - bf2f(h2h));                              \
            h2out[gp * 128 + j] = (unsigned)h2h | ((unsigned)h2l << 16);            \
        }
    #pragma unroll
    for (int t = 0; t < 2; ++t) {
        int j = jb + (t << 4);
        float bi = b_iou[j], bo = b_iou[128 + j], bu = b_iou[256 + j], bfv = b_f[j];
        EPI(accA, 0)
        EPI(accB, 1)
    }
    #undef EPI
}

// ---------------- fp32 VALU macros for the top kernel (verified R4/R5) ----------------
#define ULOOP(KB, KE, HLROW, HRROW)                                             \
    _Pragma("unroll 2")                                                         \
    for (int k4 = (KB); k4 < (KE); k4 += 4) {                                   \
        float4 u0 = Up[(k4 + 0) * H_DIM + j];                                   \
        float4 u1 = Up[(k4 + 1) * H_DIM + j];                                   \
        float4 u2 = Up[(k4 + 2) * H_DIM + j];                                   \
        float4 u3 = Up[(k4 + 3) * H_DIM + j];                                   \
        _Pragma("unroll")                                                       \
        for (int g = 0; g < G; ++g) {                                           \
            float4 hl4 = *reinterpret_cast<const float4*>((HLROW) + k4);        \
            float4 hr4 = *reinterpret_cast<const float4*>((HRROW) + k4);        \
            float hs_;                                                          \
            hs_ = hl4.x + hr4.x;                                                \
            acc_i[g] = fmaf(hs_, u0.x, acc_i[g]);                               \
            acc_o[g] = fmaf(hs_, u0.y, acc_o[g]);                               \
            acc_u[g] = fmaf(hs_, u0.z, acc_u[g]);                               \
            acc_fl[g] = fmaf(hl4.x, u0.w, acc_fl[g]);                           \
            acc_fr[g] = fmaf(hr4.x, u0.w, acc_fr[g]);                           \
            hs_ = hl4.y + hr4.y;                                                \
            acc_i[g] = fmaf(hs_, u1.x, acc_i[g]);                               \
            acc_o[g] = fmaf(hs_, u1.y, acc_o[g]);                               \
            acc_u[g] = fmaf(hs_, u1.z, acc_u[g]);                               \
            acc_fl[g] = fmaf(hl4.y, u1.w, acc_fl[g]);                           \
            acc_fr[g] = fmaf(hr4.y, u1.w, acc_fr[g]);                           \
            hs_ = hl4.z + hr4.z;                                                \
            acc_i[g] = fmaf(hs_, u2.x, acc_i[g]);                               \
            acc_o[g] = fmaf(hs_, u2.y, acc_o[g]);                               \
            acc_u[g] = fmaf(hs_, u2.z, acc_u[g]);                               \
            acc_fl[g] = fmaf(hl4.z, u2.w, acc_fl[g]);                           \
            acc_fr[g] = fmaf(hr4.z, u2.w, acc_fr[g]);                           \
            hs_ = hl4.w + hr4.w;                                                \
            acc_i[g] = fmaf(hs_, u3.x, acc_i[g]);                               \
            acc_o[g] = fmaf(hs_, u3.y, acc_o[g]);                               \
            acc_u[g] = fmaf(hs_, u3.z, acc_u[g]);                               \
            acc_fl[g] = fmaf(hl4.w, u3.w, acc_fl[g]);                           \
            acc_fr[g] = fmaf(hr4.w, u3.w, acc_fr[g]);                           \
        }                                                                       \
    }

#define WLOOP(FS, WITH_F)                                                       \
    _Pragma("unroll 2")                                                         \
    for (int k4 = 0; k4 < F_IN; k4 += 4) {                                      \
        float4 w0 = Wp[(k4 + 0) * H_DIM + j];                                   \
        float4 w1 = Wp[(k4 + 1) * H_DIM + j];                                   \
        float4 w2 = Wp[(k4 + 2) * H_DIM + j];                                   \
        float4 w3 = Wp[(k4 + 3) * H_DIM + j];                                   \
        _Pragma("unroll")                                                       \
        for (int g = 0; g < G; ++g) {                                           \
            float4 f4 = *reinterpret_cast<const float4*>((FS) + g * F_IN + k4); \
            acc_i[g] = fmaf(f4.x, w0.x, acc_i[g]);                              \
            acc_o[g] = fmaf(f4.x, w0.y, acc_o[g]);                              \
            acc_u[g] = fmaf(f4.x, w0.z, acc_u[g]);                              \
            if (WITH_F) acc_f[g] = fmaf(f4.x, w0.w, acc_f[g]);                  \
            acc_i[g] = fmaf(f4.y, w1.x, acc_i[g]);                              \
            acc_o[g] = fmaf(f4.y, w1.y, acc_o[g]);                              \
            acc_u[g] = fmaf(f4.y, w1.z, acc_u[g]);                              \
            if (WITH_F) acc_f[g] = fmaf(f4.y, w1.w, acc_f[g]);                  \
            acc_i[g] = fmaf(f4.z, w2.x, acc_i[g]);                              \
            acc_o[g] = fmaf(f4.z, w2.y, acc_o[g]);                              \
            acc_u[g] = fmaf(f4.z, w2.z, acc_u[g]);                              \
            if (WITH_F) acc_f[g] = fmaf(f4.z, w2.w, acc_f[g]);                  \
            acc_i[g] = fmaf(f4.w, w3.x, acc_i[g]);                              \
            acc_o[g] = fmaf(f4.w, w3.y, acc_o[g]);                              \
            acc_u[g] = fmaf(f4.w, w3.z, acc_u[g]);                              \
            if (WITH_F) acc_f[g] = fmaf(f4.w, w3.w, acc_f[g]);                  \
        }                                                                       \
    }

// ---------------- fused top levels (heap L3..L0), 1 block/tree (verified) ----------------
__global__ __launch_bounds__(256) void tree_top_kernel(
    const float* __restrict__ feat, const float4* __restrict__ Wp,
    const float* __restrict__ b_iou, const float4* __restrict__ Up,
    const float* __restrict__ b_f,
    float* __restrict__ h, float* __restrict__ c)
{
    const int tree = blockIdx.x;
    const int tid = threadIdx.x;
    const int j = tid & 127;
    const int grp = tid >> 7;

    __shared__ float h_s[31][H_DIM];
    __shared__ float c_s[31][H_DIM];
    __shared__ float feat_s[2 * 4 * F_IN];
    __shared__ float red5[5][H_DIM];

    for (int idx = tid; idx < 16 * H_DIM; idx += 256) {
        int loc = 15 + (idx >> 7);
        int col = idx & 127;
        size_t n = (size_t)(tree * S_NODES + loc);
        h_s[loc][col] = h[n * H_DIM + col];
        c_s[loc][col] = c[n * H_DIM + col];
    }
    __syncthreads();

    float bi = b_iou[j], bo = b_iou[128 + j], bu = b_iou[256 + j], bf = b_f[j];

    #define TOP_SLOT(G_, BASE_)                                                      \
    {                                                                                \
        constexpr int G = G_;                                                        \
        const int base = BASE_;                                                      \
        for (int idx = tid; idx < 2 * G * F_IN; idx += 256) {                        \
            int gg = idx >> 6, kk = idx & 63;                                        \
            int local = base + gg;                                                   \
            feat_s[idx] = feat[(size_t)(tree * S_NODES + local) * F_IN + kk];        \
        }                                                                            \
        __syncthreads();                                                             \
        float acc_i[G], acc_o[G], acc_u[G], acc_f[G], acc_fl[G], acc_fr[G];          \
        _Pragma("unroll")                                                            \
        for (int g = 0; g < G; ++g) {                                                \
            acc_i[g] = bi; acc_o[g] = bo; acc_u[g] = bu;                             \
            acc_f[g] = bf; acc_fl[g] = 0.f; acc_fr[g] = 0.f;                         \
        }                                                                            \
        const float* fs = feat_s + grp * G * F_IN;                                   \
        WLOOP(fs, true)                                                              \
        ULOOP(0, H_DIM, &h_s[2 * (base + grp * G + g) + 1][0],                       \
                         &h_s[2 * (base + grp * G + g) + 2][0])                      \
        _Pragma("unroll")                                                            \
        for (int g = 0; g < G; ++g) {                                                \
            int p = base + grp * G + g;                                              \
            float cl = c_s[2 * p + 1][j];                                            \
            float cr = c_s[2 * p + 2][j];                                            \
            float cn = fsig(acc_i[g]) * ftanh_(acc_u[g]);                            \
            float fl = fsig(acc_f[g] + acc_fl[g]);                                   \
            float fr = fsig(acc_f[g] + acc_fr[g]);                                   \
            cn = fmaf(fl, cl, fmaf(fr, cr, cn));                                     \
            float hn = fsig(acc_o[g]) * ftanh_(cn);                                  \
            h_s[p][j] = hn;                                                          \
            c_s[p][j] = cn;                                                          \
            h[(size_t)(tree * S_NODES + p) * H_DIM + j] = hn;                        \
        }                                                                            \
        __syncthreads();                                                             \
    }

    TOP_SLOT(4, 7)
    TOP_SLOT(2, 3)
    TOP_SLOT(1, 1)
    #undef TOP_SLOT

    {
        constexpr int G = 1;
        constexpr int KS = 44;
        if (tid < F_IN) feat_s[tid] = feat[(size_t)(tree * S_NODES) * F_IN + tid];
        __syncthreads();
        float acc_i[1], acc_o[1], acc_u[1], acc_f[1], acc_fl[1], acc_fr[1];
        if (grp == 0) {
            acc_i[0] = bi; acc_o[0] = bo; acc_u[0] = bu;
            acc_f[0] = bf; acc_fl[0] = 0.f; acc_fr[0] = 0.f;
            WLOOP(feat_s, true)
            ULOOP(0, KS, &h_s[1][0], &h_s[2][0])
        } else {
            acc_i[0] = 0.f; acc_o[0] = 0.f; acc_u[0] = 0.f;
            acc_f[0] = 0.f; acc_fl[0] = 0.f; acc_fr[0] = 0.f;
            ULOOP(KS, H_DIM, &h_s[1][0], &h_s[2][0])
        }
        __syncthreads();
        if (grp == 1) {
            red5[0][j] = acc_i[0];
            red5[1][j] = acc_o[0];
            red5[2][j] = acc_u[0];
            red5[3][j] = acc_fl[0];
            red5[4][j] = acc_fr[0];
        }
        __syncthreads();
        if (grp == 0) {
            acc_i[0] += red5[0][j];
            acc_o[0] += red5[1][j];
            acc_u[0] += red5[2][j];
            acc_fl[0] += red5[3][j];
            acc_fr[0] += red5[4][j];
            float cl = c_s[1][j], cr = c_s[2][j];
            float cn = fsig(acc_i[0]) * ftanh_(acc_u[0]);
            float fl = fsig(acc_f[0] + acc_fl[0]);
            float fr = fsig(acc_f[0] + acc_fr[0]);
            cn = fmaf(fl, cl, fmaf(fr, cr, cn));
            float hn = fsig(acc_o[0]) * ftanh_(cn);
            h[(size_t)(tree * S_NODES) * H_DIM + j] = hn;
        }
    }
}

// ---------------- readout (verified) ----------------
__global__ __launch_bounds__(512) void readout_kernel(
    const float* __restrict__ h,
    const float* __restrict__ lin1_w, const float* __restrict__ lin1_b,
    const float* __restrict__ lin2_w, const float* __restrict__ lin2_b,
    const float* __restrict__ lin_w, const float* __restrict__ lin_b,
    float* __restrict__ out)
{
    const int b = blockIdx.x;
    const int tid = threadIdx.x;
    const int q = tid >> 7;
    const int j = tid & 127;
    const float* hb = h + (size_t)b * S_NODES * H_DIM;

    float s = 0.f;
    #pragma unroll 4
    for (int n = q; n < S_NODES; n += 4) s += hb[n * H_DIM + j];

    __shared__ float part[4][H_DIM];
    __shared__ float xs[H_DIM];
    __shared__ float ys[H_DIM];
    __shared__ float red[2];

    part[q][j] = s;
    __syncthreads();
    if (tid < 128) {
        float t = (part[0][j] + part[1][j] + part[2][j] + part[3][j]) * (1.0f / 255.0f);
        xs[j] = fmaxf(t, 0.f);
    }
    __syncthreads();
    if (tid < 128) {
        float a = lin1_b[j];
        #pragma unroll 4
        for (int k = 0; k < H_DIM; ++k) a = fmaf(xs[k], lin1_w[k * H_DIM + j], a);
        ys[j] = fmaxf(a, 0.f);
    }
    __syncthreads();
    if (tid < 128) {
        float z = lin2_b[j];
        #pragma unroll 4
        for (int k = 0; k < H_DIM; ++k) z = fmaf(ys[k], lin2_w[k * H_DIM + j], z);
        z = fmaxf(z, 0.f);
        float t = z * lin_w[j];
        #pragma unroll
        for (int off = 32; off > 0; off >>= 1) t += __shfl_down(t, off, 64);
        if ((j & 63) == 0) red[j >> 6] = t;
    }
    __syncthreads();
    if (tid == 0) out[b] = red[0] + red[1] + lin_b[0];
}

extern "C" void kernel_launch(void* const* d_in, const int* in_sizes, int n_in,
                              void* d_out, int out_size, void* d_ws, size_t ws_size,
                              hipStream_t stream)
{
    const float* feat   = (const float*)d_in[0];
    const float* W_iou  = (const float*)d_in[1];
    const float* b_iou  = (const float*)d_in[2];
    const float* U_iou  = (const float*)d_in[3];
    const float* W_f    = (const float*)d_in[4];
    const float* b_f    = (const float*)d_in[5];
    const float* U_f    = (const float*)d_in[6];
    const float* lin1_w = (const float*)d_in[7];
    const float* lin1_b = (const float*)d_in[8];
    const float* lin2_w = (const float*)d_in[9];
    const float* lin2_b = (const float*)d_in[10];
    const float* lin_w  = (const float*)d_in[11];
    const float* lin_b  = (const float*)d_in[12];
    float* out = (float*)d_out;

    char* wsb = (char*)d_ws;
    float4* Wp = (float4*)wsb;                                   // 128 KB
    float4* Up = (float4*)(wsb + 131072);                        // 256 KB
    unsigned short* Btu = (unsigned short*)(wsb + 393216);       // 384 KB
    unsigned short* Btl = (unsigned short*)(wsb + 786432);       // 96 KB
    float* h  = (float*)(wsb + 884736);                          // 33.4 MB
    float* c  = (float*)(wsb + 884736 + (size_t)33423360);       // 33.4 MB
    unsigned int* h2 = (unsigned int*)(wsb + 884736 + 2 * (size_t)33423360); // 33.4 MB

    prep_bt<<<480, 256, 0, stream>>>(U_iou, U_f, W_iou, W_f, Btu, Btl);
    pack_weights<<<96, 256, 0, stream>>>(W_iou, W_f, U_iou, U_f, Wp, Up);

    // leaves: heap L7, 32768 nodes, 32/block
    leafgemm<<<1024, 256, 0, stream>>>(feat, Btl, b_iou, h, c, h2);

    // internal MFMA levels: 16 nodes (32 child rows)/block
    ugemm<<<1024, 256, 0, stream>>>(feat, h2, Btu, b_iou, b_f, h, c, h2, 63, 6); // heap L6
    ugemm<<<512,  256, 0, stream>>>(feat, h2, Btu, b_iou, b_f, h, c, h2, 31, 5); // heap L5
    ugemm<<<256,  256, 0, stream>>>(feat, h2, Btu, b_iou, b_f, h, c, h2, 15, 4); // heap L4

    // heap L3..L0 fused (VALU), one block per tree
    tree_top_kernel<<<B_TREES, 256, 0, stream>>>(feat, Wp, b_iou, Up, b_f, h, c);

    readout_kernel<<<B_TREES, 512, 0, stream>>>(
        h, lin1_w, lin1_b, lin2_w, lin2_b, lin_w, lin_b, out);
}

// Round 7
// 248.630 us; speedup vs baseline: 1.2120x; 1.2120x over previous
//
#include <hip/hip_runtime.h>
#include <hip/hip_bf16.h>
#include <math.h>

#define S_NODES 255
#define B_TREES 256
#define F_IN 64
#define H_DIM 128

typedef __attribute__((ext_vector_type(8))) short short8;
typedef __attribute__((ext_vector_type(4))) float f32x4;

__device__ __forceinline__ float fsig(float x) {
    float e = __expf(-x);
    return __builtin_amdgcn_rcpf(1.0f + e);
}
__device__ __forceinline__ float ftanh_(float x) {
    x = fminf(fmaxf(x, -15.0f), 15.0f);
    float e = __expf(2.0f * x);
    return (e - 1.0f) * __builtin_amdgcn_rcpf(e + 1.0f);
}
__device__ __forceinline__ unsigned short f2bf(float x) {
    union { __hip_bfloat16 b; unsigned short u; } v; v.b = __float2bfloat16(x); return v.u;
}
__device__ __forceinline__ float bf2f(unsigned short u) {
    union { unsigned int w; float f; } v; v.w = ((unsigned int)u) << 16; return v.f;
}
__device__ __forceinline__ unsigned int packsplit(float x) {
    unsigned short hi = f2bf(x);
    unsigned short lo = f2bf(x - bf2f(hi));
    return (unsigned)hi | ((unsigned)lo << 16);
}
__device__ __forceinline__ float unpacksplit(unsigned int u) {
    return bf2f((unsigned short)(u & 0xffffu)) + bf2f((unsigned short)(u >> 16));
}

// ---------------- prep: split-bf16 B matrices (fragment-contiguous) ----------------
// Btu[n][384] shorts: k''<192 hi, >=192 lo. k<128: U rows; [128,192): W rows.
//   cols n<384: U_iou / 0.5*W_iou ; n>=384: U_f / W_f
// Btl[n][128] shorts: k<64 hi, >=64 lo of W_iou (leaf), n<384
__global__ __launch_bounds__(256) void prep_bt(
    const float* __restrict__ U_iou, const float* __restrict__ U_f,
    const float* __restrict__ W_iou, const float* __restrict__ W_f,
    unsigned short* __restrict__ Btu, unsigned short* __restrict__ Btl)
{
    int t = blockIdx.x * 256 + threadIdx.x;
    if (t < 512 * 192) {
        int k = t >> 9, n = t & 511;
        float v;
        if (k < 128) v = (n < 384) ? U_iou[k * 384 + n] : U_f[k * 128 + (n - 384)];
        else {
            int kf = k - 128;
            v = (n < 384) ? 0.5f * W_iou[kf * 384 + n] : W_f[kf * 128 + (n - 384)];
        }
        unsigned short hi = f2bf(v);
        Btu[n * 384 + k] = hi;
        Btu[n * 384 + 192 + k] = f2bf(v - bf2f(hi));
    } else {
        int t2 = t - 512 * 192;   // < 384*64
        int k = t2 & 63, n = t2 >> 6;
        float v = W_iou[k * 384 + n];
        unsigned short hi = f2bf(v);
        Btl[n * 128 + k] = hi;
        Btl[n * 128 + 64 + k] = f2bf(v - bf2f(hi));
    }
}

// ---------------- pack fp32 weights for the top kernel ----------------
__global__ __launch_bounds__(256) void pack_weights(
    const float* __restrict__ W_iou, const float* __restrict__ W_f,
    const float* __restrict__ U_iou, const float* __restrict__ U_f,
    float4* __restrict__ Wp, float4* __restrict__ Up)
{
    int t = blockIdx.x * 256 + threadIdx.x;
    if (t < F_IN * H_DIM) {
        int k = t >> 7, j = t & 127;
        Wp[t] = make_float4(W_iou[k * 384 + j], W_iou[k * 384 + 128 + j],
                            W_iou[k * 384 + 256 + j], W_f[k * H_DIM + j]);
    } else {
        int t2 = t - F_IN * H_DIM;
        int k = t2 >> 7, j = t2 & 127;
        Up[t2] = make_float4(U_iou[k * 384 + j], U_iou[k * 384 + 128 + j],
                             U_iou[k * 384 + 256 + j], U_f[k * H_DIM + j]);
    }
}

#define MFMA(a, b, c) __builtin_amdgcn_mfma_f32_16x16x32_bf16(a, b, c, 0, 0, 0)

// ---------------- leaf GEMM: 64 leaves/block, 8 waves; B reg-double-buffered ----------------
// Wave w owns cols j = 16w..16w+15 for all 3 gates (ct = gate).
__global__ __launch_bounds__(512, 2) void leafgemm(
    const float* __restrict__ feat, const unsigned short* __restrict__ Btl,
    const float* __restrict__ b_iou,
    float* __restrict__ c_out, unsigned int* __restrict__ h2out)
{
    __shared__ __align__(16) char Alb[64 * 272];   // 17.4 KB, stride 272 => 2-way banks
    const int tid = threadIdx.x;
    const int w = tid >> 6, l = tid & 63;
    const int l15 = l & 15, l4 = l >> 4;
    const int NB = blockIdx.x << 6;

    int nct[3];
    #pragma unroll
    for (int ct = 0; ct < 3; ++ct) nct[ct] = (ct << 7) + (w << 4) + l15;

    short8 Bh[2][3], Bl[2][3];
    #define LLOADB(buf, ss) { int chb = ((ss) << 2) + l4;                         \
        _Pragma("unroll") for (int ct = 0; ct < 3; ++ct) {                        \
            const char* bp = (const char*)Btl + (size_t)nct[ct] * 256 + (chb << 4); \
            Bh[buf][ct] = *(const short8*)(bp);                                   \
            Bl[buf][ct] = *(const short8*)(bp + 128); } }

    LLOADB(0, 0)   // overlap with A-stage

    // A stage: 64 rows x (8 hi + 8 lo) chunks; 1 task/thread
    {
        int row = tid >> 3, o = tid & 7;
        int leafidx = NB + row;
        int tree = leafidx >> 7;
        size_t grow = (size_t)(tree * S_NODES + 127 + (leafidx & 127));
        const float* fp = feat + grow * F_IN + (o << 3);
        float4 va = *(const float4*)(fp);
        float4 vb = *(const float4*)(fp + 4);
        float vv[8] = {va.x, va.y, va.z, va.w, vb.x, vb.y, vb.z, vb.w};
        unsigned int qh[4], ql[4];
        #pragma unroll
        for (int e = 0; e < 4; ++e) {
            unsigned short h0 = f2bf(vv[2*e]), h1 = f2bf(vv[2*e+1]);
            unsigned short s0 = f2bf(vv[2*e] - bf2f(h0));
            unsigned short s1 = f2bf(vv[2*e+1] - bf2f(h1));
            qh[e] = (unsigned)h0 | ((unsigned)h1 << 16);
            ql[e] = (unsigned)s0 | ((unsigned)s1 << 16);
        }
        char* arow = Alb + row * 272;
        *(uint4*)(arow + (o << 4)) = make_uint4(qh[0], qh[1], qh[2], qh[3]);
        *(uint4*)(arow + ((8 + o) << 4)) = make_uint4(ql[0], ql[1], ql[2], ql[3]);
    }
    __syncthreads();

    f32x4 acc[4][3];
    #pragma unroll
    for (int rt = 0; rt < 4; ++rt)
        #pragma unroll
        for (int ct = 0; ct < 3; ++ct) acc[rt][ct] = (f32x4){0,0,0,0};

    #pragma unroll
    for (int s = 0; s < 2; ++s) {
        const int cur = s & 1;
        if (s < 1) LLOADB(1, 1)
        int ch = (s << 2) + l4;
        short8 ah[4], al[4];
        #pragma unroll
        for (int rt = 0; rt < 4; ++rt) {
            const char* ap = Alb + (rt * 16 + l15) * 272;
            ah[rt] = *(const short8*)(ap + (ch << 4));
            al[rt] = *(const short8*)(ap + ((8 + ch) << 4));
        }
        #pragma unroll
        for (int ct = 0; ct < 3; ++ct)
            #pragma unroll
            for (int rt = 0; rt < 4; ++rt) {
                acc[rt][ct] = MFMA(ah[rt], Bh[cur][ct], acc[rt][ct]);
                acc[rt][ct] = MFMA(al[rt], Bh[cur][ct], acc[rt][ct]);
                acc[rt][ct] = MFMA(ah[rt], Bl[cur][ct], acc[rt][ct]);
            }
    }

    // epilogue: gates lane-local; C layout col=lane&15, row=(lane>>4)*4+reg
    const int j = (w << 4) + l15;
    float bi = b_iou[j], bo = b_iou[128 + j], bu = b_iou[256 + j];
    #pragma unroll
    for (int rt = 0; rt < 4; ++rt)
        #pragma unroll
        for (int rr = 0; rr < 4; ++rr) {
            int leafrow = rt * 16 + (l4 << 2) + rr;
            int leafidx = NB + leafrow;
            int tree = leafidx >> 7;
            size_t grow = (size_t)(tree * S_NODES + 127 + (leafidx & 127));
            float iv = acc[rt][0][rr] + bi;
            float ov = acc[rt][1][rr] + bo;
            float uv = acc[rt][2][rr] + bu;
            float cn = fsig(iv) * ftanh_(uv);
            float hn = fsig(ov) * ftanh_(cn);
            c_out[grow * 128 + j] = cn;
            h2out[grow * 128 + j] = packsplit(hn);
        }
    #undef LLOADB
}

// ---------------- internal-level GEMM: 32 nodes (64 child rows)/block, 8 waves ----------------
// A-row = [h_child(128) | feat_parent(64)] split-bf16 in LDS. B direct from Btu,
// register double-buffered across the 6 k-slices. Wave w owns cols j=16w..16w+15 x 4 gates.
__global__ __launch_bounds__(512, 2) void ugemm(
    const float* __restrict__ feat, const unsigned int* __restrict__ h2,
    const unsigned short* __restrict__ Btu,
    const float* __restrict__ b_iou, const float* __restrict__ b_f,
    float* __restrict__ c_io, unsigned int* __restrict__ h2out,
    int Lstart, int Lbits)
{
    __shared__ __align__(16) char Alb[64 * 784];   // 50.2 KB, stride 784 => 2-way banks
    const int tid = threadIdx.x;
    const int w = tid >> 6, l = tid & 63;
    const int l15 = l & 15, l4 = l >> 4;
    const int NB = blockIdx.x << 5;
    const int mask = (1 << Lbits) - 1;

    int nct[4];
    #pragma unroll
    for (int ct = 0; ct < 4; ++ct)
        nct[ct] = ((ct < 3) ? (ct << 7) : 384) + (w << 4) + l15;

    short8 Bh[2][4], Bl[2][4];
    #define ULOADB(buf, ss) { int chb = ((ss) << 2) + l4;                         \
        _Pragma("unroll") for (int ct = 0; ct < 4; ++ct) {                        \
            const char* bp = (const char*)Btu + (size_t)nct[ct] * 768 + (chb << 4); \
            Bh[buf][ct] = *(const short8*)(bp);                                   \
            Bl[buf][ct] = *(const short8*)(bp + 384); } }

    ULOADB(0, 0)   // overlap with A-stage

    // ---- A stage: 64 rows x 48 chunks (0..15 h-hi, 16..23 f-hi, 24..39 h-lo, 40..47 f-lo)
    #pragma unroll
    for (int i = 0; i < 2; ++i) {      // h tasks: 1024
        int tsk = tid + (i << 9);
        int row = tsk >> 4, o = tsk & 15;
        int node = NB + (row >> 1);
        int tree = node >> Lbits;
        int local = Lstart + (node & mask);
        size_t growc = (size_t)(tree * S_NODES + 2 * local + 1 + (row & 1));
        const unsigned int* hp = h2 + growc * 128 + (o << 3);
        uint4 a = *(const uint4*)(hp);
        uint4 b = *(const uint4*)(hp + 4);
        uint4 vh, vl;
        vh.x = (a.x & 0xffffu) | (a.y << 16);
        vh.y = (a.z & 0xffffu) | (a.w << 16);
        vh.z = (b.x & 0xffffu) | (b.y << 16);
        vh.w = (b.z & 0xffffu) | (b.w << 16);
        vl.x = (a.x >> 16) | (a.y & 0xffff0000u);
        vl.y = (a.z >> 16) | (a.w & 0xffff0000u);
        vl.z = (b.x >> 16) | (b.y & 0xffff0000u);
        vl.w = (b.z >> 16) | (b.w & 0xffff0000u);
        char* arow = Alb + row * 784;
        *(uint4*)(arow + (o << 4)) = vh;
        *(uint4*)(arow + ((24 + o) << 4)) = vl;
    }
    {                                   // feat tasks: 512
        int t2 = tid;
        int row = t2 >> 3, o = t2 & 7;
        int node = NB + (row >> 1);
        int tree = node >> Lbits;
        int local = Lstart + (node & mask);
        size_t growp = (size_t)(tree * S_NODES + local);
        const float* fp = feat + growp * F_IN + (o << 3);
        float4 va = *(const float4*)(fp);
        float4 vb = *(const float4*)(fp + 4);
        float vv[8] = {va.x, va.y, va.z, va.w, vb.x, vb.y, vb.z, vb.w};
        unsigned int qh[4], ql[4];
        #pragma unroll
        for (int e = 0; e < 4; ++e) {
            unsigned short h0 = f2bf(vv[2*e]), h1 = f2bf(vv[2*e+1]);
            unsigned short s0 = f2bf(vv[2*e] - bf2f(h0));
            unsigned short s1 = f2bf(vv[2*e+1] - bf2f(h1));
            qh[e] = (unsigned)h0 | ((unsigned)h1 << 16);
            ql[e] = (unsigned)s0 | ((unsigned)s1 << 16);
        }
        char* arow = Alb + row * 784;
        *(uint4*)(arow + ((16 + o) << 4)) = make_uint4(qh[0], qh[1], qh[2], qh[3]);
        *(uint4*)(arow + ((40 + o) << 4)) = make_uint4(ql[0], ql[1], ql[2], ql[3]);
    }
    __syncthreads();

    f32x4 acc[4][4];
    #pragma unroll
    for (int rt = 0; rt < 4; ++rt)
        #pragma unroll
        for (int ct = 0; ct < 4; ++ct) acc[rt][ct] = (f32x4){0,0,0,0};

    #pragma unroll
    for (int s = 0; s < 6; ++s) {
        const int cur = s & 1;
        if (s < 5) ULOADB(cur ^ 1, s + 1)
        int ch = (s << 2) + l4;
        short8 ah[4], al[4];
        #pragma unroll
        for (int rt = 0; rt < 4; ++rt) {
            const char* ap = Alb + (rt * 16 + l15) * 784;
            ah[rt] = *(const short8*)(ap + (ch << 4));
            al[rt] = *(const short8*)(ap + ((24 + ch) << 4));
        }
        #pragma unroll
        for (int ct = 0; ct < 4; ++ct)
            #pragma unroll
            for (int rt = 0; rt < 4; ++rt) {
                acc[rt][ct] = MFMA(ah[rt], Bh[cur][ct], acc[rt][ct]);
                acc[rt][ct] = MFMA(al[rt], Bh[cur][ct], acc[rt][ct]);
                acc[rt][ct] = MFMA(ah[rt], Bl[cur][ct], acc[rt][ct]);
            }
    }

    // ---- epilogue: gates lane-local; node m = rt*8 + l4*2 + p, child row-pair in rr ----
    const int j = (w << 4) + l15;
    float bi = b_iou[j], bo = b_iou[128 + j], bu = b_iou[256 + j], bfv = b_f[j];
    #pragma unroll
    for (int rt = 0; rt < 4; ++rt)
        #pragma unroll
        for (int p = 0; p < 2; ++p) {
            int m = rt * 8 + (l4 << 1) + p;
            int node = NB + m;
            int tree = node >> Lbits;
            int local = Lstart + (node & mask);
            size_t gp = (size_t)(tree * S_NODES + local);
            size_t gl = (size_t)(tree * S_NODES + 2 * local + 1);
            float iv = acc[rt][0][2*p] + acc[rt][0][2*p+1] + bi;
            float ov = acc[rt][1][2*p] + acc[rt][1][2*p+1] + bo;
            float uv = acc[rt][2][2*p] + acc[rt][2][2*p+1] + bu;
            float fl = fsig(acc[rt][3][2*p] + bfv);
            float fr = fsig(acc[rt][3][2*p+1] + bfv);
            float cl = c_io[gl * 128 + j];
            float cr = c_io[(gl + 1) * 128 + j];
            float cn = fsig(iv) * ftanh_(uv) + fl * cl + fr * cr;
            float hn = fsig(ov) * ftanh_(cn);
            c_io[gp * 128 + j] = cn;
            h2out[gp * 128 + j] = packsplit(hn);
        }
    #undef ULOADB
}

// ---------------- fp32 VALU macros for the top kernel (verified R4/R5/R6) ----------------
#define ULOOP(KB, KE, HLROW, HRROW)                                             \
    _Pragma("unroll 2")                                                         \
    for (int k4 = (KB); k4 < (KE); k4 += 4) {                                   \
        float4 u0 = Up[(k4 + 0) * H_DIM + j];                                   \
        float4 u1 = Up[(k4 + 1) * H_DIM + j];                                   \
        float4 u2 = Up[(k4 + 2) * H_DIM + j];                                   \
        float4 u3 = Up[(k4 + 3) * H_DIM + j];                                   \
        _Pragma("unroll")                                                       \
        for (int g = 0; g < G; ++g) {                                           \
            float4 hl4 = *reinterpret_cast<const float4*>((HLROW) + k4);        \
            float4 hr4 = *reinterpret_cast<const float4*>((HRROW) + k4);        \
            float hs_;                                                          \
            hs_ = hl4.x + hr4.x;                                                \
            acc_i[g] = fmaf(hs_, u0.x, acc_i[g]);                               \
            acc_o[g] = fmaf(hs_, u0.y, acc_o[g]);                               \
            acc_u[g] = fmaf(hs_, u0.z, acc_u[g]);                               \
            acc_fl[g] = fmaf(hl4.x, u0.w, acc_fl[g]);                           \
            acc_fr[g] = fmaf(hr4.x, u0.w, acc_fr[g]);                           \
            hs_ = hl4.y + hr4.y;                                                \
            acc_i[g] = fmaf(hs_, u1.x, acc_i[g]);                               \
            acc_o[g] = fmaf(hs_, u1.y, acc_o[g]);                               \
            acc_u[g] = fmaf(hs_, u1.z, acc_u[g]);                               \
            acc_fl[g] = fmaf(hl4.y, u1.w, acc_fl[g]);                           \
            acc_fr[g] = fmaf(hr4.y, u1.w, acc_fr[g]);                           \
            hs_ = hl4.z + hr4.z;                                                \
            acc_i[g] = fmaf(hs_, u2.x, acc_i[g]);                               \
            acc_o[g] = fmaf(hs_, u2.y, acc_o[g]);                               \
            acc_u[g] = fmaf(hs_, u2.z, acc_u[g]);                               \
            acc_fl[g] = fmaf(hl4.z, u2.w, acc_fl[g]);                           \
            acc_fr[g] = fmaf(hr4.z, u2.w, acc_fr[g]);                           \
            hs_ = hl4.w + hr4.w;                                                \
            acc_i[g] = fmaf(hs_, u3.x, acc_i[g]);                               \
            acc_o[g] = fmaf(hs_, u3.y, acc_o[g]);                               \
            acc_u[g] = fmaf(hs_, u3.z, acc_u[g]);                               \
            acc_fl[g] = fmaf(hl4.w, u3.w, acc_fl[g]);                           \
            acc_fr[g] = fmaf(hr4.w, u3.w, acc_fr[g]);                           \
        }                                                                       \
    }

#define WLOOP(FS, WITH_F)                                                       \
    _Pragma("unroll 2")                                                         \
    for (int k4 = 0; k4 < F_IN; k4 += 4) {                                      \
        float4 w0 = Wp[(k4 + 0) * H_DIM + j];                                   \
        float4 w1 = Wp[(k4 + 1) * H_DIM + j];                                   \
        float4 w2 = Wp[(k4 + 2) * H_DIM + j];                                   \
        float4 w3 = Wp[(k4 + 3) * H_DIM + j];                                   \
        _Pragma("unroll")                                                       \
        for (int g = 0; g < G; ++g) {                                           \
            float4 f4 = *reinterpret_cast<const float4*>((FS) + g * F_IN + k4); \
            acc_i[g] = fmaf(f4.x, w0.x, acc_i[g]);                              \
            acc_o[g] = fmaf(f4.x, w0.y, acc_o[g]);                              \
            acc_u[g] = fmaf(f4.x, w0.z, acc_u[g]);                              \
            if (WITH_F) acc_f[g] = fmaf(f4.x, w0.w, acc_f[g]);                  \
            acc_i[g] = fmaf(f4.y, w1.x, acc_i[g]);                              \
            acc_o[g] = fmaf(f4.y, w1.y, acc_o[g]);                              \
            acc_u[g] = fmaf(f4.y, w1.z, acc_u[g]);                              \
            if (WITH_F) acc_f[g] = fmaf(f4.y, w1.w, acc_f[g]);                  \
            acc_i[g] = fmaf(f4.z, w2.x, acc_i[g]);                              \
            acc_o[g] = fmaf(f4.z, w2.y, acc_o[g]);                              \
            acc_u[g] = fmaf(f4.z, w2.z, acc_u[g]);                              \
            if (WITH_F) acc_f[g] = fmaf(f4.z, w2.w, acc_f[g]);                  \
            acc_i[g] = fmaf(f4.w, w3.x, acc_i[g]);                              \
            acc_o[g] = fmaf(f4.w, w3.y, acc_o[g]);                              \
            acc_u[g] = fmaf(f4.w, w3.z, acc_u[g]);                              \
            if (WITH_F) acc_f[g] = fmaf(f4.w, w3.w, acc_f[g]);                  \
        }                                                                       \
    }

// ---------------- fused top levels (heap L3..L0), 1 block/tree; h via h2 ----------------
__global__ __launch_bounds__(256) void tree_top_kernel(
    const float* __restrict__ feat, const float4* __restrict__ Wp,
    const float* __restrict__ b_iou, const float4* __restrict__ Up,
    const float* __restrict__ b_f,
    unsigned int* __restrict__ h2g, float* __restrict__ c)
{
    const int tree = blockIdx.x;
    const int tid = threadIdx.x;
    const int j = tid & 127;
    const int grp = tid >> 7;

    __shared__ float h_s[31][H_DIM];
    __shared__ float c_s[31][H_DIM];
    __shared__ float feat_s[2 * 4 * F_IN];
    __shared__ float red5[5][H_DIM];

    for (int idx = tid; idx < 16 * H_DIM; idx += 256) {
        int loc = 15 + (idx >> 7);
        int col = idx & 127;
        size_t n = (size_t)(tree * S_NODES + loc);
        h_s[loc][col] = unpacksplit(h2g[n * H_DIM + col]);
        c_s[loc][col] = c[n * H_DIM + col];
    }
    __syncthreads();

    float bi = b_iou[j], bo = b_iou[128 + j], bu = b_iou[256 + j], bf = b_f[j];

    #define TOP_SLOT(G_, BASE_)                                                      \
    {                                                                                \
        constexpr int G = G_;                                                        \
        const int base = BASE_;                                                      \
        for (int idx = tid; idx < 2 * G * F_IN; idx += 256) {                        \
            int gg = idx >> 6, kk = idx & 63;                                        \
            int local = base + gg;                                                   \
            feat_s[idx] = feat[(size_t)(tree * S_NODES + local) * F_IN + kk];        \
        }                                                                            \
        __syncthreads();                                                             \
        float acc_i[G], acc_o[G], acc_u[G], acc_f[G], acc_fl[G], acc_fr[G];          \
        _Pragma("unroll")                                                            \
        for (int g = 0; g < G; ++g) {                                                \
            acc_i[g] = bi; acc_o[g] = bo; acc_u[g] = bu;                             \
            acc_f[g] = bf; acc_fl[g] = 0.f; acc_fr[g] = 0.f;                         \
        }                                                                            \
        const float* fs = feat_s + grp * G * F_IN;                                   \
        WLOOP(fs, true)                                                              \
        ULOOP(0, H_DIM, &h_s[2 * (base + grp * G + g) + 1][0],                       \
                         &h_s[2 * (base + grp * G + g) + 2][0])                      \
        _Pragma("unroll")                                                            \
        for (int g = 0; g < G; ++g) {                                                \
            int p = base + grp * G + g;                                              \
            float cl = c_s[2 * p + 1][j];                                            \
            float cr = c_s[2 * p + 2][j];                                            \
            float cn = fsig(acc_i[g]) * ftanh_(acc_u[g]);                            \
            float fl = fsig(acc_f[g] + acc_fl[g]);                                   \
            float fr = fsig(acc_f[g] + acc_fr[g]);                                   \
            cn = fmaf(fl, cl, fmaf(fr, cr, cn));                                     \
            float hn = fsig(acc_o[g]) * ftanh_(cn);                                  \
            h_s[p][j] = hn;                                                          \
            c_s[p][j] = cn;                                                          \
            h2g[(size_t)(tree * S_NODES + p) * H_DIM + j] = packsplit(hn);           \
        }                                                                            \
        __syncthreads();                                                             \
    }

    TOP_SLOT(4, 7)
    TOP_SLOT(2, 3)
    TOP_SLOT(1, 1)
    #undef TOP_SLOT

    {
        constexpr int G = 1;
        constexpr int KS = 44;
        if (tid < F_IN) feat_s[tid] = feat[(size_t)(tree * S_NODES) * F_IN + tid];
        __syncthreads();
        float acc_i[1], acc_o[1], acc_u[1], acc_f[1], acc_fl[1], acc_fr[1];
        if (grp == 0) {
            acc_i[0] = bi; acc_o[0] = bo; acc_u[0] = bu;
            acc_f[0] = bf; acc_fl[0] = 0.f; acc_fr[0] = 0.f;
            WLOOP(feat_s, true)
            ULOOP(0, KS, &h_s[1][0], &h_s[2][0])
        } else {
            acc_i[0] = 0.f; acc_o[0] = 0.f; acc_u[0] = 0.f;
            acc_f[0] = 0.f; acc_fl[0] = 0.f; acc_fr[0] = 0.f;
            ULOOP(KS, H_DIM, &h_s[1][0], &h_s[2][0])
        }
        __syncthreads();
        if (grp == 1) {
            red5[0][j] = acc_i[0];
            red5[1][j] = acc_o[0];
            red5[2][j] = acc_u[0];
            red5[3][j] = acc_fl[0];
            red5[4][j] = acc_fr[0];
        }
        __syncthreads();
        if (grp == 0) {
            acc_i[0] += red5[0][j];
            acc_o[0] += red5[1][j];
            acc_u[0] += red5[2][j];
            acc_fl[0] += red5[3][j];
            acc_fr[0] += red5[4][j];
            float cl = c_s[1][j], cr = c_s[2][j];
            float cn = fsig(acc_i[0]) * ftanh_(acc_u[0]);
            float fl = fsig(acc_f[0] + acc_fl[0]);
            float fr = fsig(acc_f[0] + acc_fr[0]);
            cn = fmaf(fl, cl, fmaf(fr, cr, cn));
            float hn = fsig(acc_o[0]) * ftanh_(cn);
            h2g[(size_t)(tree * S_NODES) * H_DIM + j] = packsplit(hn);
        }
    }
}

// ---------------- readout (h via h2 reconstruct) ----------------
__global__ __launch_bounds__(512) void readout_kernel(
    const unsigned int* __restrict__ h2,
    const float* __restrict__ lin1_w, const float* __restrict__ lin1_b,
    const float* __restrict__ lin2_w, const float* __restrict__ lin2_b,
    const float* __restrict__ lin_w, const float* __restrict__ lin_b,
    float* __restrict__ out)
{
    const int b = blockIdx.x;
    const int tid = threadIdx.x;
    const int q = tid >> 7;
    const int j = tid & 127;
    const unsigned int* hb = h2 + (size_t)b * S_NODES * H_DIM;

    float s = 0.f;
    #pragma unroll 4
    for (int n = q; n < S_NODES; n += 4) s += unpacksplit(hb[n * H_DIM + j]);

    __shared__ float part[4][H_DIM];
    __shared__ float xs[H_DIM];
    __shared__ float ys[H_DIM];
    __shared__ float red[2];

    part[q][j] = s;
    __syncthreads();
    if (tid < 128) {
        float t = (part[0][j] + part[1][j] + part[2][j] + part[3][j]) * (1.0f / 255.0f);
        xs[j] = fmaxf(t, 0.f);
    }
    __syncthreads();
    if (tid < 128) {
        float a = lin1_b[j];
        #pragma unroll 4
        for (int k = 0; k < H_DIM; ++k) a = fmaf(xs[k], lin1_w[k * H_DIM + j], a);
        ys[j] = fmaxf(a, 0.f);
    }
    __syncthreads();
    if (tid < 128) {
        float z = lin2_b[j];
        #pragma unroll 4
        for (int k = 0; k < H_DIM; ++k) z = fmaf(ys[k], lin2_w[k * H_DIM + j], z);
        z = fmaxf(z, 0.f);
        float t = z * lin_w[j];
        #pragma unroll
        for (int off = 32; off > 0; off >>= 1) t += __shfl_down(t, off, 64);
        if ((j & 63) == 0) red[j >> 6] = t;
    }
    __syncthreads();
    if (tid == 0) out[b] = red[0] + red[1] + lin_b[0];
}

extern "C" void kernel_launch(void* const* d_in, const int* in_sizes, int n_in,
                              void* d_out, int out_size, void* d_ws, size_t ws_size,
                              hipStream_t stream)
{
    const float* feat   = (const float*)d_in[0];
    const float* W_iou  = (const float*)d_in[1];
    const float* b_iou  = (const float*)d_in[2];
    const float* U_iou  = (const float*)d_in[3];
    const float* W_f    = (const float*)d_in[4];
    const float* b_f    = (const float*)d_in[5];
    const float* U_f    = (const float*)d_in[6];
    const float* lin1_w = (const float*)d_in[7];
    const float* lin1_b = (const float*)d_in[8];
    const float* lin2_w = (const float*)d_in[9];
    const float* lin2_b = (const float*)d_in[10];
    const float* lin_w  = (const float*)d_in[11];
    const float* lin_b  = (const float*)d_in[12];
    float* out = (float*)d_out;

    char* wsb = (char*)d_ws;
    float4* Wp = (float4*)wsb;                                   // 128 KB
    float4* Up = (float4*)(wsb + 131072);                        // 256 KB
    unsigned short* Btu = (unsigned short*)(wsb + 393216);       // 384 KB
    unsigned short* Btl = (unsigned short*)(wsb + 786432);       // 96 KB
    float* c  = (float*)(wsb + 884736);                          // 33.4 MB
    unsigned int* h2 = (unsigned int*)(wsb + 884736 + (size_t)33423360); // 33.4 MB

    prep_bt<<<480, 256, 0, stream>>>(U_iou, U_f, W_iou, W_f, Btu, Btl);
    pack_weights<<<96, 256, 0, stream>>>(W_iou, W_f, U_iou, U_f, Wp, Up);

    // leaves: heap L7, 32768 nodes, 64/block
    leafgemm<<<512, 512, 0, stream>>>(feat, Btl, b_iou, c, h2);

    // internal MFMA levels: 32 nodes (64 child rows)/block
    ugemm<<<512, 512, 0, stream>>>(feat, h2, Btu, b_iou, b_f, c, h2, 63, 6); // heap L6
    ugemm<<<256, 512, 0, stream>>>(feat, h2, Btu, b_iou, b_f, c, h2, 31, 5); // heap L5
    ugemm<<<128, 512, 0, stream>>>(feat, h2, Btu, b_iou, b_f, c, h2, 15, 4); // heap L4

    // heap L3..L0 fused (VALU), one block per tree
    tree_top_kernel<<<B_TREES, 256, 0, stream>>>(feat, Wp, b_iou, Up, b_f, h2, c);

    readout_kernel<<<B_TREES, 512, 0, stream>>>(
        h2, lin1_w, lin1_b, lin2_w, lin2_b, lin_w, lin_b, out);
}